// Round 1
// 957.250 us; speedup vs baseline: 1.0191x; 1.0191x over previous
//
#include <hip/hip_runtime.h>

// Problem constants
#define N_    8
#define CH_   512
#define SD_   512
#define CIG_  8
#define NG_   64
#define H_    128
#define W_    128
#define HW_   16384
#define KDW   2048        // 512 ci * 4 (2x2 window)
#define NP_   72          // 8 n * 9 kernel positions
#define OC_   4096        // CH_*CIG_

// Workspace layout (floats). Total 786432 floats = 3.0 MB.
#define WS_B     0
#define WS_SPOOL (WS_B + NP_ * KDW)          // 147456
#define WS_PWKN  (WS_SPOOL + N_ * SD_)       // 151552
#define WS_PWB   (WS_PWKN + N_ * OC_)        // 184320
#define WS_DW    (WS_PWB + N_ * CH_)         // 188416
#define WS_E     (WS_DW + N_ * OC_ * 9)      // 483328
#define WS_MEAN  (WS_E + N_ * OC_ * 9)       // 778240
#define WS_RSTD  (WS_MEAN + N_ * CH_)        // 782336

// Zero range: pwkn (32768) + pwbias (4096) + dwacc (294912) are contiguous.
#define NZERO (N_ * OC_ + N_ * CH_ + N_ * OC_ * 9)   // 331776

// ---------------------------------------------------------------------------
// prep: im2col of style (B[np][k]), style avg-pool (spool),
//       zero pwkn/pwbias/dwacc (contiguous, atomically accumulated later)
// ---------------------------------------------------------------------------
__global__ __launch_bounds__(256) void prep(const float* __restrict__ style,
                                            float* __restrict__ B,
                                            float* __restrict__ spool,
                                            float* __restrict__ zbase) {
  const int idx = blockIdx.x * 256 + threadIdx.x;
  const int NB = NP_ * KDW;        // 147456
  const int NS = N_ * SD_;         // 4096
  if (idx < NB) {
    const int np = idx >> 11;
    const int k = idx & 2047;
    const int n = np / 9, p = np % 9;
    const int py = p / 3, px = p % 3;
    const int ci = k >> 2, uv = k & 3;
    const int u = uv >> 1, v = uv & 1;
    B[idx] = style[(n * SD_ + ci) * 16 + (py + u) * 4 + (px + v)];
  } else if (idx < NB + NS) {
    const int j = idx - NB;
    const float* s = style + j * 16;
    float a = 0.f;
#pragma unroll
    for (int t = 0; t < 16; t++) a += s[t];
    spool[j] = a * (1.0f / 16.0f);
  } else if (idx < NB + NS + NZERO) {
    zbase[idx - NB - NS] = 0.0f;
  }
}

// ---------------------------------------------------------------------------
// stats: per-(n,c) mean and 1/sqrt(var_unbiased + 1e-5) over 128x128
// ---------------------------------------------------------------------------
__global__ __launch_bounds__(256) void stats(const float* __restrict__ pred,
                                             float* __restrict__ meanv,
                                             float* __restrict__ rstdv) {
  const int nc = blockIdx.x;  // 0..4095
  const float4* p = (const float4*)(pred + (size_t)nc * HW_);
  float s = 0.f, s2 = 0.f;
#pragma unroll
  for (int i = 0; i < 16; i++) {
    const float4 v = p[threadIdx.x + 256 * i];
    s += v.x + v.y + v.z + v.w;
    s2 += v.x * v.x + v.y * v.y + v.z * v.z + v.w * v.w;
  }
  for (int off = 32; off > 0; off >>= 1) {
    s += __shfl_down(s, off, 64);
    s2 += __shfl_down(s2, off, 64);
  }
  __shared__ float as[4], as2[4];
  const int wv = threadIdx.x >> 6;
  if ((threadIdx.x & 63) == 0) { as[wv] = s; as2[wv] = s2; }
  __syncthreads();
  if (threadIdx.x == 0) {
    const float S = as[0] + as[1] + as[2] + as[3];
    const float S2 = as2[0] + as2[1] + as2[2] + as2[3];
    const float mean = S * (1.0f / HW_);
    const float var = (S2 - S * mean) * (1.0f / (HW_ - 1));
    meanv[nc] = mean;
    rstdv[nc] = 1.0f / sqrtf(var + 1e-5f);
  }
}

// ---------------------------------------------------------------------------
// pw_gemm: pw_kn (8x4096) and pw_bias (8x512); K=512 split 4-way
// (blockIdx.y), partial sums atomically added into zeroed outputs.
// Bias added by the y==0 block only.
// ---------------------------------------------------------------------------
__global__ __launch_bounds__(256) void pw_gemm(const float* __restrict__ spool,
                                               const float* __restrict__ pkw,
                                               const float* __restrict__ pkb,
                                               const float* __restrict__ pbw,
                                               const float* __restrict__ pbb,
                                               float* __restrict__ pwkn,
                                               float* __restrict__ pwbias) {
  __shared__ float sp[N_ * 128];
  const int kb = blockIdx.y * 128;
  for (int i = threadIdx.x; i < N_ * 128; i += 256) {
    const int nn = i >> 7, kk = i & 127;
    sp[i] = spool[nn * SD_ + kb + kk];
  }
  __syncthreads();
  const int col = blockIdx.x * 256 + threadIdx.x;  // 0..4607
  const float* w;
  float bias;
  if (col < OC_) { w = pkw + (size_t)col * SD_ + kb; bias = pkb[col]; }
  else           { w = pbw + (size_t)(col - OC_) * SD_ + kb; bias = pbb[col - OC_]; }
  float acc[8];
#pragma unroll
  for (int nn = 0; nn < 8; nn++) acc[nn] = 0.f;
  for (int k = 0; k < 128; k += 4) {
    const float4 wv = *(const float4*)(w + k);
#pragma unroll
    for (int nn = 0; nn < 8; nn++) {
      const float4 sv = *(const float4*)(&sp[nn * 128 + k]);
      acc[nn] = fmaf(wv.x, sv.x, acc[nn]);
      acc[nn] = fmaf(wv.y, sv.y, acc[nn]);
      acc[nn] = fmaf(wv.z, sv.z, acc[nn]);
      acc[nn] = fmaf(wv.w, sv.w, acc[nn]);
    }
  }
  const float badd = (blockIdx.y == 0) ? bias : 0.0f;
  if (col < OC_) {
#pragma unroll
    for (int nn = 0; nn < 8; nn++)
      atomicAdd(&pwkn[nn * OC_ + col], acc[nn] + badd);
  } else {
#pragma unroll
    for (int nn = 0; nn < 8; nn++)
      atomicAdd(&pwbias[nn * CH_ + (col - OC_)], acc[nn] + badd);
  }
}

// ---------------------------------------------------------------------------
// dw_gemm: dw[np=72][co=4096], K=2048. Grid (32 co-tiles, 16 K-splits).
// W (dw_w) transposed into LDS [k][co] (stride 129 -> conflict-free b32 reads).
// B read via wave-uniform scalar loads (readfirstlane forces SGPR path).
// Partial sums accumulated with fp32 atomics into zeroed dwacc.
// ---------------------------------------------------------------------------
__global__ __launch_bounds__(256) void dw_gemm(const float* __restrict__ Bg,
                                               const float* __restrict__ Wg,
                                               float* __restrict__ dwacc) {
  __shared__ float Wl[64 * 129];
  const int t = threadIdx.x;
  const int co0 = blockIdx.x * 128;
  const int kbase = blockIdx.y * 128;
  const int co = t & 127;
  const int npb = __builtin_amdgcn_readfirstlane((t >> 7) * 36);
  float acc[36];
#pragma unroll
  for (int j = 0; j < 36; j++) acc[j] = 0.f;

  for (int kc = 0; kc < 128; kc += 64) {
    __syncthreads();
    {
      const int kq = (t & 15) * 4;
      const int cob = t >> 4;
#pragma unroll
      for (int r = 0; r < 8; r++) {
        const int c = cob + r * 16;
        const float4 wv =
            *(const float4*)(Wg + (size_t)(co0 + c) * KDW + kbase + kc + kq);
        Wl[(kq + 0) * 129 + c] = wv.x;
        Wl[(kq + 1) * 129 + c] = wv.y;
        Wl[(kq + 2) * 129 + c] = wv.z;
        Wl[(kq + 3) * 129 + c] = wv.w;
      }
    }
    __syncthreads();
    const float* Bp = Bg + kbase + kc;
    for (int k = 0; k < 64; k += 4) {
      const float w0 = Wl[(k + 0) * 129 + co];
      const float w1 = Wl[(k + 1) * 129 + co];
      const float w2 = Wl[(k + 2) * 129 + co];
      const float w3 = Wl[(k + 3) * 129 + co];
#pragma unroll
      for (int j = 0; j < 36; j++) {
        const float4 b = *(const float4*)(Bp + (npb + j) * KDW + k);
        float a = acc[j];
        a = fmaf(w0, b.x, a);
        a = fmaf(w1, b.y, a);
        a = fmaf(w2, b.z, a);
        a = fmaf(w3, b.w, a);
        acc[j] = a;
      }
    }
  }
#pragma unroll
  for (int j = 0; j < 36; j++) {
    const int np = npb + j;
    const int n = np / 9, p = np % 9;
    atomicAdd(dwacc + (size_t)(n * OC_ + co0 + co) * 9 + p, acc[j]);
  }
}

// ---------------------------------------------------------------------------
// eff_k: fold pointwise into depthwise: E[n][gc][ci][p][co] =
//        sum_j pw_kn[n][gc*8+co][j] * (dw[n][(gc*8+j)*8+ci][p] + dw_b[...])
// ---------------------------------------------------------------------------
__global__ __launch_bounds__(256) void eff_k(const float* __restrict__ dwacc,
                                             const float* __restrict__ dwb,
                                             const float* __restrict__ pwkn,
                                             float* __restrict__ Eg) {
  const int idx = blockIdx.x * 256 + threadIdx.x;  // < 294912
  const int co = idx & 7;
  int tmp = idx >> 3;
  const int p = tmp % 9;
  tmp /= 9;
  const int ci = tmp & 7;
  tmp >>= 3;
  const int gc = tmp & 63;
  const int n = tmp >> 6;
  const int c = gc * 8 + co;
  float a = 0.f;
#pragma unroll
  for (int j = 0; j < 8; j++) {
    const int ch = (gc * 8 + j) * 8 + ci;
    a = fmaf(pwkn[n * OC_ + c * 8 + j],
             dwacc[(size_t)(n * OC_ + ch) * 9 + p] + dwb[ch], a);
  }
  Eg[idx] = a;
}

// ---------------------------------------------------------------------------
// main_conv: instance-norm + reflect-pad + effective 8-in/8-out 3x3 conv
// Block: (ytile 16 rows, group gc, sample n). 256 threads, 8co x 8px/thread.
// ci is processed in two chunks of 4, staged through a half-size LDS tile:
// LDS = 4*18*132*4 + 576*4 + 64 = 40384 B  ->  4 blocks/CU (was 2 at 78.8 KB).
// Accumulation order over ci is unchanged (identical numerics).
// ---------------------------------------------------------------------------
#define ROWS 16
__global__ __launch_bounds__(256, 4) void main_conv(
    const float* __restrict__ pred, const float* __restrict__ Eg,
    const float* __restrict__ pwb, const float* __restrict__ meanv,
    const float* __restrict__ rstdv, float* __restrict__ out) {
  __shared__ float xl[4 * 18 * 132];   // 38016 B
  __shared__ float El[8 * 9 * 8];      // [ci][p][co]
  __shared__ float cm[8], cr[8];
  const int t = threadIdx.x;
  const int yt = blockIdx.x;  // 0..7
  const int gc = blockIdx.y;  // 0..63
  const int n = blockIdx.z;   // 0..7
  const int chbase = n * CH_ + gc * 8;

  if (t < 8) {
    cm[t] = meanv[chbase + t];
    cr[t] = rstdv[chbase + t];
  }
  for (int i = t; i < 576; i += 256)
    El[i] = Eg[(size_t)(n * 64 + gc) * 576 + i];
  __syncthreads();

  const int y0 = yt * ROWS;
  const int y = t >> 4;          // 0..15
  const int xb = (t & 15) * 8;   // 0..120
  float acc[8][8];
#pragma unroll
  for (int co = 0; co < 8; co++)
#pragma unroll
    for (int px = 0; px < 8; px++) acc[co][px] = 0.f;

#pragma unroll 1
  for (int half = 0; half < 2; half++) {
    if (half) __syncthreads();  // prior compute must finish before overwrite
    for (int i = t; i < 4 * 18 * 130; i += 256) {
      const int col = i % 130;
      const int rr = (i / 130) % 18;
      const int cl = i / (130 * 18);   // local ci 0..3
      const int ci = half * 4 + cl;
      int gy = y0 + rr - 1;
      gy = gy < 0 ? -gy : (gy > 127 ? 254 - gy : gy);
      int gx = col - 1;
      gx = gx < 0 ? -gx : (gx > 127 ? 254 - gx : gx);
      const float v = pred[((size_t)(chbase + ci) * 128 + gy) * 128 + gx];
      xl[(cl * 18 + rr) * 132 + col] = (v - cm[ci]) * cr[ci];
    }
    __syncthreads();

#pragma unroll 1
    for (int cl = 0; cl < 4; cl++) {
      const int ci = half * 4 + cl;
#pragma unroll
      for (int ky = 0; ky < 3; ky++) {
        const float* xr = &xl[(cl * 18 + y + ky) * 132 + xb];
        const float4 xa = *(const float4*)(xr);
        const float4 xc = *(const float4*)(xr + 4);
        const float xw[10] = {xa.x, xa.y, xa.z, xa.w, xc.x,
                              xc.y, xc.z, xc.w, xr[8], xr[9]};
#pragma unroll
        for (int kx = 0; kx < 3; kx++) {
          const float4 e0 = *(const float4*)(&El[(ci * 9 + ky * 3 + kx) * 8]);
          const float4 e1 =
              *(const float4*)(&El[(ci * 9 + ky * 3 + kx) * 8 + 4]);
          const float ev[8] = {e0.x, e0.y, e0.z, e0.w,
                               e1.x, e1.y, e1.z, e1.w};
#pragma unroll
          for (int co = 0; co < 8; co++)
#pragma unroll
            for (int px = 0; px < 8; px++)
              acc[co][px] = fmaf(ev[co], xw[kx + px], acc[co][px]);
        }
      }
    }
  }

  const int gy = y0 + y;
#pragma unroll
  for (int co = 0; co < 8; co++) {
    const float b = pwb[chbase + co];
    float* op = out + ((size_t)(chbase + co) * 128 + gy) * 128 + xb;
    float4 o0, o1;
    o0.x = acc[co][0] + b; o0.y = acc[co][1] + b;
    o0.z = acc[co][2] + b; o0.w = acc[co][3] + b;
    o1.x = acc[co][4] + b; o1.y = acc[co][5] + b;
    o1.z = acc[co][6] + b; o1.w = acc[co][7] + b;
    *(float4*)op = o0;
    *(float4*)(op + 4) = o1;
  }
}

// ---------------------------------------------------------------------------
extern "C" void kernel_launch(void* const* d_in, const int* in_sizes, int n_in,
                              void* d_out, int out_size, void* d_ws,
                              size_t ws_size, hipStream_t stream) {
  const float* style = (const float*)d_in[0];
  const float* pred = (const float*)d_in[1];
  const float* dww = (const float*)d_in[2];
  const float* dwb = (const float*)d_in[3];
  const float* pkw = (const float*)d_in[4];
  const float* pkb = (const float*)d_in[5];
  const float* pbw = (const float*)d_in[6];
  const float* pbb = (const float*)d_in[7];
  float* out = (float*)d_out;
  float* ws = (float*)d_ws;

  float* B = ws + WS_B;
  float* spool = ws + WS_SPOOL;
  float* pwkn = ws + WS_PWKN;
  float* pwbias = ws + WS_PWB;
  float* dwacc = ws + WS_DW;
  float* Eg = ws + WS_E;
  float* meanv = ws + WS_MEAN;
  float* rstdv = ws + WS_RSTD;

  // prep covers im2col (147456) + spool (4096) + zero range (331776) = 483328
  prep<<<dim3(1888), dim3(256), 0, stream>>>(style, B, spool, pwkn);
  stats<<<dim3(4096), dim3(256), 0, stream>>>(pred, meanv, rstdv);
  pw_gemm<<<dim3(18, 4), dim3(256), 0, stream>>>(spool, pkw, pkb, pbw, pbb,
                                                 pwkn, pwbias);
  dw_gemm<<<dim3(32, 16), dim3(256), 0, stream>>>(B, dww, dwacc);
  eff_k<<<dim3(1152), dim3(256), 0, stream>>>(dwacc, dwb, pwkn, Eg);
  main_conv<<<dim3(8, 64, 8), dim3(256), 0, stream>>>(pred, Eg, pwbias, meanv,
                                                      rstdv, out);
}

// Round 3
// 815.373 us; speedup vs baseline: 1.1964x; 1.1740x over previous
//
#include <hip/hip_runtime.h>

// Problem constants
#define N_    8
#define CH_   512
#define SD_   512
#define CIG_  8
#define NG_   64
#define H_    128
#define W_    128
#define HW_   16384
#define KDW   2048        // 512 ci * 4 (2x2 window)
#define NP_   72          // 8 n * 9 kernel positions
#define OC_   4096        // CH_*CIG_

// Workspace layout (floats). Total 786432 floats = 3.0 MB.
#define WS_B     0
#define WS_SPOOL (WS_B + NP_ * KDW)          // 147456
#define WS_PWKN  (WS_SPOOL + N_ * SD_)       // 151552
#define WS_PWB   (WS_PWKN + N_ * OC_)        // 184320
#define WS_DW    (WS_PWB + N_ * CH_)         // 188416
#define WS_E     (WS_DW + N_ * OC_ * 9)      // 483328
#define WS_MEAN  (WS_E + N_ * OC_ * 9)       // 778240
#define WS_RSTD  (WS_MEAN + N_ * CH_)        // 782336

// Zero range: pwkn (32768) + pwbias (4096) + dwacc (294912) are contiguous.
#define NZERO (N_ * OC_ + N_ * CH_ + N_ * OC_ * 9)   // 331776

// ---------------------------------------------------------------------------
// prep: im2col of style (B[np][k]), style avg-pool (spool),
//       zero pwkn/pwbias/dwacc (contiguous, atomically accumulated later)
// ---------------------------------------------------------------------------
__global__ __launch_bounds__(256) void prep(const float* __restrict__ style,
                                            float* __restrict__ B,
                                            float* __restrict__ spool,
                                            float* __restrict__ zbase) {
  const int idx = blockIdx.x * 256 + threadIdx.x;
  const int NB = NP_ * KDW;        // 147456
  const int NS = N_ * SD_;         // 4096
  if (idx < NB) {
    const int np = idx >> 11;
    const int k = idx & 2047;
    const int n = np / 9, p = np % 9;
    const int py = p / 3, px = p % 3;
    const int ci = k >> 2, uv = k & 3;
    const int u = uv >> 1, v = uv & 1;
    B[idx] = style[(n * SD_ + ci) * 16 + (py + u) * 4 + (px + v)];
  } else if (idx < NB + NS) {
    const int j = idx - NB;
    const float* s = style + j * 16;
    float a = 0.f;
#pragma unroll
    for (int t = 0; t < 16; t++) a += s[t];
    spool[j] = a * (1.0f / 16.0f);
  } else if (idx < NB + NS + NZERO) {
    zbase[idx - NB - NS] = 0.0f;
  }
}

// ---------------------------------------------------------------------------
// stats: per-(n,c) mean and 1/sqrt(var_unbiased + 1e-5) over 128x128
// ---------------------------------------------------------------------------
__global__ __launch_bounds__(256) void stats(const float* __restrict__ pred,
                                             float* __restrict__ meanv,
                                             float* __restrict__ rstdv) {
  const int nc = blockIdx.x;  // 0..4095
  const float4* p = (const float4*)(pred + (size_t)nc * HW_);
  float s = 0.f, s2 = 0.f;
#pragma unroll
  for (int i = 0; i < 16; i++) {
    const float4 v = p[threadIdx.x + 256 * i];
    s += v.x + v.y + v.z + v.w;
    s2 += v.x * v.x + v.y * v.y + v.z * v.z + v.w * v.w;
  }
  for (int off = 32; off > 0; off >>= 1) {
    s += __shfl_down(s, off, 64);
    s2 += __shfl_down(s2, off, 64);
  }
  __shared__ float as[4], as2[4];
  const int wv = threadIdx.x >> 6;
  if ((threadIdx.x & 63) == 0) { as[wv] = s; as2[wv] = s2; }
  __syncthreads();
  if (threadIdx.x == 0) {
    const float S = as[0] + as[1] + as[2] + as[3];
    const float S2 = as2[0] + as2[1] + as2[2] + as2[3];
    const float mean = S * (1.0f / HW_);
    const float var = (S2 - S * mean) * (1.0f / (HW_ - 1));
    meanv[nc] = mean;
    rstdv[nc] = 1.0f / sqrtf(var + 1e-5f);
  }
}

// ---------------------------------------------------------------------------
// pw_gemm: pw_kn (8x4096) and pw_bias (8x512); K=512 split 4-way
// (blockIdx.y), partial sums atomically added into zeroed outputs.
// Bias added by the y==0 block only.
// ---------------------------------------------------------------------------
__global__ __launch_bounds__(256) void pw_gemm(const float* __restrict__ spool,
                                               const float* __restrict__ pkw,
                                               const float* __restrict__ pkb,
                                               const float* __restrict__ pbw,
                                               const float* __restrict__ pbb,
                                               float* __restrict__ pwkn,
                                               float* __restrict__ pwbias) {
  __shared__ float sp[N_ * 128];
  const int kb = blockIdx.y * 128;
  for (int i = threadIdx.x; i < N_ * 128; i += 256) {
    const int nn = i >> 7, kk = i & 127;
    sp[i] = spool[nn * SD_ + kb + kk];
  }
  __syncthreads();
  const int col = blockIdx.x * 256 + threadIdx.x;  // 0..4607
  const float* w;
  float bias;
  if (col < OC_) { w = pkw + (size_t)col * SD_ + kb; bias = pkb[col]; }
  else           { w = pbw + (size_t)(col - OC_) * SD_ + kb; bias = pbb[col - OC_]; }
  float acc[8];
#pragma unroll
  for (int nn = 0; nn < 8; nn++) acc[nn] = 0.f;
  for (int k = 0; k < 128; k += 4) {
    const float4 wv = *(const float4*)(w + k);
#pragma unroll
    for (int nn = 0; nn < 8; nn++) {
      const float4 sv = *(const float4*)(&sp[nn * 128 + k]);
      acc[nn] = fmaf(wv.x, sv.x, acc[nn]);
      acc[nn] = fmaf(wv.y, sv.y, acc[nn]);
      acc[nn] = fmaf(wv.z, sv.z, acc[nn]);
      acc[nn] = fmaf(wv.w, sv.w, acc[nn]);
    }
  }
  const float badd = (blockIdx.y == 0) ? bias : 0.0f;
  if (col < OC_) {
#pragma unroll
    for (int nn = 0; nn < 8; nn++)
      atomicAdd(&pwkn[nn * OC_ + col], acc[nn] + badd);
  } else {
#pragma unroll
    for (int nn = 0; nn < 8; nn++)
      atomicAdd(&pwbias[nn * CH_ + (col - OC_)], acc[nn] + badd);
  }
}

// ---------------------------------------------------------------------------
// dw_gemm: dw[np=72][co=4096], K=2048. Grid (32 co-tiles, 16 K-splits).
// W (dw_w) transposed into LDS [k][co] (stride 129 -> conflict-free b32 reads).
// B read via wave-uniform scalar loads (readfirstlane forces SGPR path).
// Partial sums accumulated with fp32 atomics into zeroed dwacc.
// ---------------------------------------------------------------------------
__global__ __launch_bounds__(256) void dw_gemm(const float* __restrict__ Bg,
                                               const float* __restrict__ Wg,
                                               float* __restrict__ dwacc) {
  __shared__ float Wl[64 * 129];
  const int t = threadIdx.x;
  const int co0 = blockIdx.x * 128;
  const int kbase = blockIdx.y * 128;
  const int co = t & 127;
  const int npb = __builtin_amdgcn_readfirstlane((t >> 7) * 36);
  float acc[36];
#pragma unroll
  for (int j = 0; j < 36; j++) acc[j] = 0.f;

  for (int kc = 0; kc < 128; kc += 64) {
    __syncthreads();
    {
      const int kq = (t & 15) * 4;
      const int cob = t >> 4;
#pragma unroll
      for (int r = 0; r < 8; r++) {
        const int c = cob + r * 16;
        const float4 wv =
            *(const float4*)(Wg + (size_t)(co0 + c) * KDW + kbase + kc + kq);
        Wl[(kq + 0) * 129 + c] = wv.x;
        Wl[(kq + 1) * 129 + c] = wv.y;
        Wl[(kq + 2) * 129 + c] = wv.z;
        Wl[(kq + 3) * 129 + c] = wv.w;
      }
    }
    __syncthreads();
    const float* Bp = Bg + kbase + kc;
    for (int k = 0; k < 64; k += 4) {
      const float w0 = Wl[(k + 0) * 129 + co];
      const float w1 = Wl[(k + 1) * 129 + co];
      const float w2 = Wl[(k + 2) * 129 + co];
      const float w3 = Wl[(k + 3) * 129 + co];
#pragma unroll
      for (int j = 0; j < 36; j++) {
        const float4 b = *(const float4*)(Bp + (npb + j) * KDW + k);
        float a = acc[j];
        a = fmaf(w0, b.x, a);
        a = fmaf(w1, b.y, a);
        a = fmaf(w2, b.z, a);
        a = fmaf(w3, b.w, a);
        acc[j] = a;
      }
    }
  }
#pragma unroll
  for (int j = 0; j < 36; j++) {
    const int np = npb + j;
    const int n = np / 9, p = np % 9;
    atomicAdd(dwacc + (size_t)(n * OC_ + co0 + co) * 9 + p, acc[j]);
  }
}

// ---------------------------------------------------------------------------
// eff_k: fold pointwise into depthwise AND fold instance-norm:
//   E'[n][gc][ci][p][co] = rstd[n][gc*8+ci] * sum_j pw_kn[...] * (dw + dw_b)
//   pwbias[n][gc*8+co]  -= E' * mean[n][gc*8+ci]   (summed over ci,p)
// so main_conv consumes raw pred values (no per-element normalization).
// ---------------------------------------------------------------------------
__global__ __launch_bounds__(256) void eff_k(const float* __restrict__ dwacc,
                                             const float* __restrict__ dwb,
                                             const float* __restrict__ pwkn,
                                             const float* __restrict__ meanv,
                                             const float* __restrict__ rstdv,
                                             float* __restrict__ Eg,
                                             float* __restrict__ pwbias) {
  const int idx = blockIdx.x * 256 + threadIdx.x;  // < 294912
  const int co = idx & 7;
  int tmp = idx >> 3;
  const int p = tmp % 9;
  tmp /= 9;
  const int ci = tmp & 7;
  tmp >>= 3;
  const int gc = tmp & 63;
  const int n = tmp >> 6;
  const int c = gc * 8 + co;
  float a = 0.f;
#pragma unroll
  for (int j = 0; j < 8; j++) {
    const int ch = (gc * 8 + j) * 8 + ci;
    a = fmaf(pwkn[n * OC_ + c * 8 + j],
             dwacc[(size_t)(n * OC_ + ch) * 9 + p] + dwb[ch], a);
  }
  const int cin = n * CH_ + gc * 8 + ci;
  const float ep = a * rstdv[cin];
  Eg[idx] = ep;
  atomicAdd(&pwbias[n * CH_ + c], -ep * meanv[cin]);
}

// ---------------------------------------------------------------------------
// main_conv: reflect-pad + effective 8-in/8-out 3x3 conv (norm pre-folded).
// Block: 8-row tile, group gc, sample n. 256 threads = y(8) x ch(2) x xs(16);
// each thread: acc[4co][8px] = 32 regs.
// Staging: interior-only aligned float4 copies (reflect halo columns resolved
// at read time via li/ri since reflected values duplicate interior columns).
// LDS: 4ci*10*132 xl + 288 El-half = 22272 B -> up to 7 blocks/CU.
// No min-waves hint: natural VGPR (~70-90) avoids forced spill (round-1 found
// the allocator clamps to ~256/arg with a hint, spilling the accumulator).
// ---------------------------------------------------------------------------
#define ROWS 8
__global__ __launch_bounds__(256) void main_conv(
    const float* __restrict__ pred, const float* __restrict__ Eg,
    const float* __restrict__ pwb, float* __restrict__ out) {
  __shared__ float xl[4 * 10 * 132];   // 21120 B
  __shared__ float Elh[288];           // 1152 B, one ci-half of E
  const int t = threadIdx.x;
  const int yt = blockIdx.x;  // 0..15
  const int gc = blockIdx.y;  // 0..63
  const int n = blockIdx.z;   // 0..7
  const int chbase = n * CH_ + gc * 8;
  const int y0 = yt * ROWS;

  const int y = t >> 5;                // 0..7
  const int ch4 = ((t >> 4) & 1) * 4;  // 0 or 4 (co half)
  const int xb = (t & 15) * 8;         // 0..120
  const int li = (xb == 0) ? 1 : xb - 1;       // reflect: x[-1] = x[1]
  const int ri = (xb == 120) ? 126 : xb + 8;   // reflect: x[128] = x[126]

  float acc[4][8];
#pragma unroll
  for (int co = 0; co < 4; co++)
#pragma unroll
    for (int px = 0; px < 8; px++) acc[co][px] = 0.f;

  const float* egb = Eg + (size_t)(n * 64 + gc) * 576;

#pragma unroll 1
  for (int h = 0; h < 2; h++) {
    if (h) __syncthreads();  // prior compute must finish before overwrite
    // stage 4 input channels, rows y0-1..y0+8 (interior cols only, float4)
    for (int i = t; i < 1280; i += 256) {   // 4ci * 10rr * 32q, 5 iters
      const int ci_l = (i >> 6) / 5;        // /320
      const int r = i - ci_l * 320;
      const int rr = r >> 5;
      const int q = r & 31;
      int gy = y0 + rr - 1;
      gy = gy < 0 ? 1 : (gy > 127 ? 126 : gy);
      const float4 v = *(const float4*)(
          pred + (((size_t)(chbase + h * 4 + ci_l) << 7) + gy) * 128 +
          (q << 2));
      *(float4*)(&xl[(ci_l * 10 + rr) * 132 + (q << 2)]) = v;
    }
    for (int i = t; i < 288; i += 256) Elh[i] = egb[h * 288 + i];
    __syncthreads();

#pragma unroll 1
    for (int cl = 0; cl < 4; cl++) {
      const float* xbase = xl + cl * 1320;
#pragma unroll
      for (int ky = 0; ky < 3; ky++) {
        const float* xrow = xbase + (y + ky) * 132;
        const float4 xa = *(const float4*)(xrow + xb);
        const float4 xc = *(const float4*)(xrow + xb + 4);
        float xw[10];
        xw[0] = xrow[li];
        xw[1] = xa.x; xw[2] = xa.y; xw[3] = xa.z; xw[4] = xa.w;
        xw[5] = xc.x; xw[6] = xc.y; xw[7] = xc.z; xw[8] = xc.w;
        xw[9] = xrow[ri];
#pragma unroll
        for (int kx = 0; kx < 3; kx++) {
          const float4 e =
              *(const float4*)(&Elh[(cl * 9 + ky * 3 + kx) * 8 + ch4]);
          const float ev[4] = {e.x, e.y, e.z, e.w};
#pragma unroll
          for (int co = 0; co < 4; co++)
#pragma unroll
            for (int px = 0; px < 8; px++)
              acc[co][px] = fmaf(ev[co], xw[px + kx], acc[co][px]);
        }
      }
    }
  }

  const int gyo = y0 + y;
#pragma unroll
  for (int co = 0; co < 4; co++) {
    const int c = chbase + ch4 + co;
    const float b = pwb[c];
    float* op = out + ((size_t)c * 128 + gyo) * 128 + xb;
    float4 o0, o1;
    o0.x = acc[co][0] + b; o0.y = acc[co][1] + b;
    o0.z = acc[co][2] + b; o0.w = acc[co][3] + b;
    o1.x = acc[co][4] + b; o1.y = acc[co][5] + b;
    o1.z = acc[co][6] + b; o1.w = acc[co][7] + b;
    *(float4*)op = o0;
    *(float4*)(op + 4) = o1;
  }
}

// ---------------------------------------------------------------------------
extern "C" void kernel_launch(void* const* d_in, const int* in_sizes, int n_in,
                              void* d_out, int out_size, void* d_ws,
                              size_t ws_size, hipStream_t stream) {
  const float* style = (const float*)d_in[0];
  const float* pred = (const float*)d_in[1];
  const float* dww = (const float*)d_in[2];
  const float* dwb = (const float*)d_in[3];
  const float* pkw = (const float*)d_in[4];
  const float* pkb = (const float*)d_in[5];
  const float* pbw = (const float*)d_in[6];
  const float* pbb = (const float*)d_in[7];
  float* out = (float*)d_out;
  float* ws = (float*)d_ws;

  float* B = ws + WS_B;
  float* spool = ws + WS_SPOOL;
  float* pwkn = ws + WS_PWKN;
  float* pwbias = ws + WS_PWB;
  float* dwacc = ws + WS_DW;
  float* Eg = ws + WS_E;
  float* meanv = ws + WS_MEAN;
  float* rstdv = ws + WS_RSTD;

  // prep covers im2col (147456) + spool (4096) + zero range (331776) = 483328
  prep<<<dim3(1888), dim3(256), 0, stream>>>(style, B, spool, pwkn);
  stats<<<dim3(4096), dim3(256), 0, stream>>>(pred, meanv, rstdv);
  pw_gemm<<<dim3(18, 4), dim3(256), 0, stream>>>(spool, pkw, pkb, pbw, pbb,
                                                 pwkn, pwbias);
  dw_gemm<<<dim3(32, 16), dim3(256), 0, stream>>>(B, dww, dwacc);
  eff_k<<<dim3(1152), dim3(256), 0, stream>>>(dwacc, dwb, pwkn, meanv, rstdv,
                                              Eg, pwbias);
  main_conv<<<dim3(16, 64, 8), dim3(256), 0, stream>>>(pred, Eg, pwbias, out);
}